// Round 4
// baseline (589.350 us; speedup 1.0000x reference)
//
#include <hip/hip_runtime.h>

#define Bd 16
#define Cd 512
#define HWd 4096          // 64*64
#define NCLS 5
#define BETA 2.0f
#define EPS2 (0.001f * 0.001f)

// R2's proven channel-strided pattern (112us), but CH 16->8 so the grid is
// 4096 blocks = 2 generations of 8 blocks/CU -> scheduler backfill fixes the
// 58% occupancy of the single-generation 2048-block grid.
constexpr int CH = 8;               // channels per block
constexpr int NCCHUNK = Cd / CH;    // 64
constexpr int PIX_PER_BLOCK = 1024; // 256 threads * 4 pixels (float4)
constexpr int CSTRIDE = HWd / 4;    // float4 stride between channels (16KB)

// grid = (HW/1024, B, NCCHUNK) = (4, 16, 64) = 4096 blocks
__global__ __launch_bounds__(256, 8) void seg_partial_kernel(
    const float* __restrict__ rec, const float* __restrict__ aln,
    const int* __restrict__ mask,
    float* __restrict__ segsum, float* __restrict__ segcnt)
{
    const int tid = threadIdx.x;
    const int b   = blockIdx.y;
    const int hw0 = blockIdx.x * PIX_PER_BLOCK + tid * 4;
    const int c0  = blockIdx.z * CH;

    const size_t base = (size_t)(b * Cd + c0) * HWd + hw0;
    const float4* __restrict__ rv = (const float4*)(rec + base);
    const float4* __restrict__ av = (const float4*)(aln + base);

    float4 acc = make_float4(0.f, 0.f, 0.f, 0.f);
    // 8 dwordx4 loads issued before any use (8 KB in flight per wave) — the
    // exact shape that measured 112us in R2.
#pragma unroll
    for (int cb = 0; cb < CH; cb += 4) {
        const float4* r4 = rv + (size_t)cb * CSTRIDE;
        const float4* a4 = av + (size_t)cb * CSTRIDE;
        float4 r0 = r4[0 * CSTRIDE];
        float4 r1 = r4[1 * CSTRIDE];
        float4 r2 = r4[2 * CSTRIDE];
        float4 r3 = r4[3 * CSTRIDE];
        float4 a0 = a4[0 * CSTRIDE];
        float4 a1 = a4[1 * CSTRIDE];
        float4 a2 = a4[2 * CSTRIDE];
        float4 a3 = a4[3 * CSTRIDE];

        float d;
        d = r0.x - a0.x; acc.x += d * d;
        d = r0.y - a0.y; acc.y += d * d;
        d = r0.z - a0.z; acc.z += d * d;
        d = r0.w - a0.w; acc.w += d * d;
        d = r1.x - a1.x; acc.x += d * d;
        d = r1.y - a1.y; acc.y += d * d;
        d = r1.z - a1.z; acc.z += d * d;
        d = r1.w - a1.w; acc.w += d * d;
        d = r2.x - a2.x; acc.x += d * d;
        d = r2.y - a2.y; acc.y += d * d;
        d = r2.z - a2.z; acc.z += d * d;
        d = r2.w - a2.w; acc.w += d * d;
        d = r3.x - a3.x; acc.x += d * d;
        d = r3.y - a3.y; acc.y += d * d;
        d = r3.z - a3.z; acc.z += d * d;
        d = r3.w - a3.w; acc.w += d * d;
    }

    // mask load after the stream loop (L2-hot; shared by all 64 c-chunks)
    const int4 m = *(const int4*)(mask + b * HWd + hw0);

    // register predication (amortized over CH channels), then wave shuffle
    // reduce — avoids the per-block 1024-deep LDS atomic serialization.
    float cls[NCLS] = {0, 0, 0, 0, 0};
    {
        float v[4]  = {acc.x, acc.y, acc.z, acc.w};
        int   mm[4] = {m.x, m.y, m.z, m.w};
#pragma unroll
        for (int e = 0; e < 4; ++e) {
#pragma unroll
            for (int k = 0; k < NCLS; ++k)
                cls[k] += (mm[e] == k) ? v[e] : 0.0f;
        }
    }
#pragma unroll
    for (int k = 0; k < NCLS; ++k) {
#pragma unroll
        for (int off = 32; off > 0; off >>= 1)
            cls[k] += __shfl_down(cls[k], off, 64);
    }
    if ((tid & 63) == 0) {
        const float scale = 1.0f / (float)Cd;   // channel mean
#pragma unroll
        for (int k = 0; k < NCLS; ++k)
            atomicAdd(&segsum[b * NCLS + k], cls[k] * scale);
    }

    // counts: z==0 blocks cover each (batch, hw-quarter) exactly once
    if (blockIdx.z == 0) {
        float cnt[NCLS] = {0, 0, 0, 0, 0};
        int mm[4] = {m.x, m.y, m.z, m.w};
#pragma unroll
        for (int e = 0; e < 4; ++e) {
#pragma unroll
            for (int k = 0; k < NCLS; ++k)
                cnt[k] += (mm[e] == k) ? 1.0f : 0.0f;
        }
#pragma unroll
        for (int k = 0; k < NCLS; ++k) {
#pragma unroll
            for (int off = 32; off > 0; off >>= 1)
                cnt[k] += __shfl_down(cnt[k], off, 64);
        }
        if ((tid & 63) == 0) {
#pragma unroll
            for (int k = 0; k < NCLS; ++k)
                atomicAdd(&segcnt[b * NCLS + k], cnt[k]);
        }
    }
}

// Kernel 2: 80 segments -> scalar. One block of 128 threads.
__global__ __launch_bounds__(128) void finalize_kernel(
    const float* __restrict__ segsum, const float* __restrict__ segcnt,
    float* __restrict__ out)
{
    __shared__ float sMax[128];
    __shared__ float sSum[128];
    const int t = threadIdx.x;

    float s = 0.0f, cnt = 0.0f;
    if (t < Bd * NCLS) { s = segsum[t]; cnt = segcnt[t]; }
    const float avg = s / fmaxf(cnt, 1.0f);   // empty segments -> 0 (contribute nothing)

    sMax[t] = avg;
    __syncthreads();
#pragma unroll
    for (int off = 64; off > 0; off >>= 1) {
        if (t < off) sMax[t] = fmaxf(sMax[t], sMax[t + off]);
        __syncthreads();
    }
    const float wmax = sMax[0];

    float w = (wmax > 0.0f) ? (avg / (wmax + EPS2)) : (avg + EPS2);
    w = fminf(fmaxf(w, 0.0f), 1.0f);

    sSum[t] = s * (w * BETA + 1.0f);
    __syncthreads();
#pragma unroll
    for (int off = 64; off > 0; off >>= 1) {
        if (t < off) sSum[t] += sSum[t + off];
        __syncthreads();
    }
    if (t == 0) out[0] = sSum[0] / (float)(Bd * HWd);
}

extern "C" void kernel_launch(void* const* d_in, const int* in_sizes, int n_in,
                              void* d_out, int out_size, void* d_ws, size_t ws_size,
                              hipStream_t stream) {
    const float* rec  = (const float*)d_in[0];
    const float* aln  = (const float*)d_in[1];
    const int*   mask = (const int*)d_in[2];
    float* out = (float*)d_out;

    float* segsum = (float*)d_ws;
    float* segcnt = segsum + Bd * NCLS;

    // zero the 2*80 accumulators (ws is re-poisoned to 0xAA before every launch)
    hipMemsetAsync(d_ws, 0, 2 * Bd * NCLS * sizeof(float), stream);

    dim3 grid(HWd / PIX_PER_BLOCK, Bd, NCCHUNK);   // (4, 16, 64) = 4096 blocks
    seg_partial_kernel<<<grid, 256, 0, stream>>>(rec, aln, mask, segsum, segcnt);
    finalize_kernel<<<1, 128, 0, stream>>>(segsum, segcnt, out);
}

// Round 5
// 288.558 us; speedup vs baseline: 2.0424x; 2.0424x over previous
//
#include <hip/hip_runtime.h>

#define Bd 16
#define Cd 512
#define HWd 4096          // 64*64
#define NCLS 5
#define BETA 2.0f
#define EPS2 (0.001f * 0.001f)

// R2's proven load structure: CH=16 channels/block, 2048 blocks, 8 dwordx4
// in flight per wave. The ONLY change vs R2: the epilogue has ZERO atomics.
// Evidence (R2-R4): same-address global fp32 atomics cost ~400-600ns each
// (cross-XCD line ping-pong); R4's 1024-deep chains = 406us, R3's 512 = 327us,
// R2's 128-deep chains ~= its 112us. Each block now STORES its 5 partials to
// a private ws slot; a finalize kernel pre-reduces them.
constexpr int CH = 16;              // channels per block
constexpr int NCCHUNK = Cd / CH;    // 32
constexpr int PIX_PER_BLOCK = 1024; // 256 threads * 4 pixels (float4)
constexpr int CSTRIDE = HWd / 4;    // float4 stride between channels (16KB)
constexpr int PSTRIDE = 8;          // padded partial stride (floats)

// grid = (HW/1024, B, NCCHUNK) = (4, 16, 32) = 2048 blocks
__global__ __launch_bounds__(256, 8) void seg_partial_kernel(
    const float* __restrict__ rec, const float* __restrict__ aln,
    const int* __restrict__ mask,
    float* __restrict__ psum, float* __restrict__ pcnt)
{
    const int tid = threadIdx.x;
    const int b   = blockIdx.y;
    const int hw0 = blockIdx.x * PIX_PER_BLOCK + tid * 4;
    const int c0  = blockIdx.z * CH;

    const size_t base = (size_t)(b * Cd + c0) * HWd + hw0;
    const float4* __restrict__ rv = (const float4*)(rec + base);
    const float4* __restrict__ av = (const float4*)(aln + base);

    // mask load before the stream loop (R2 position; L2-hot, reused 32x)
    const int4 m = *(const int4*)(mask + b * HWd + hw0);

    float4 acc = make_float4(0.f, 0.f, 0.f, 0.f);
    // 8 dwordx4 loads issued before any use — R2's measured shape.
#pragma unroll
    for (int cb = 0; cb < CH; cb += 4) {
        const float4* r4 = rv + (size_t)cb * CSTRIDE;
        const float4* a4 = av + (size_t)cb * CSTRIDE;
        float4 r0 = r4[0 * CSTRIDE];
        float4 r1 = r4[1 * CSTRIDE];
        float4 r2 = r4[2 * CSTRIDE];
        float4 r3 = r4[3 * CSTRIDE];
        float4 a0 = a4[0 * CSTRIDE];
        float4 a1 = a4[1 * CSTRIDE];
        float4 a2 = a4[2 * CSTRIDE];
        float4 a3 = a4[3 * CSTRIDE];

        float d;
        d = r0.x - a0.x; acc.x += d * d;
        d = r0.y - a0.y; acc.y += d * d;
        d = r0.z - a0.z; acc.z += d * d;
        d = r0.w - a0.w; acc.w += d * d;
        d = r1.x - a1.x; acc.x += d * d;
        d = r1.y - a1.y; acc.y += d * d;
        d = r1.z - a1.z; acc.z += d * d;
        d = r1.w - a1.w; acc.w += d * d;
        d = r2.x - a2.x; acc.x += d * d;
        d = r2.y - a2.y; acc.y += d * d;
        d = r2.z - a2.z; acc.z += d * d;
        d = r2.w - a2.w; acc.w += d * d;
        d = r3.x - a3.x; acc.x += d * d;
        d = r3.y - a3.y; acc.y += d * d;
        d = r3.z - a3.z; acc.z += d * d;
        d = r3.w - a3.w; acc.w += d * d;
    }

    // register predication into 5 class accumulators
    float cls[NCLS] = {0, 0, 0, 0, 0};
    {
        float v[4]  = {acc.x, acc.y, acc.z, acc.w};
        int   mm[4] = {m.x, m.y, m.z, m.w};
#pragma unroll
        for (int e = 0; e < 4; ++e) {
#pragma unroll
            for (int k = 0; k < NCLS; ++k)
                cls[k] += (mm[e] == k) ? v[e] : 0.0f;
        }
    }
    // wave shuffle-reduce (proven cheap: VALUBusy ~2% in R3/R4)
#pragma unroll
    for (int k = 0; k < NCLS; ++k) {
#pragma unroll
        for (int off = 32; off > 0; off >>= 1)
            cls[k] += __shfl_down(cls[k], off, 64);
    }

    // block combine via plain LDS rows (no atomics), then ONE plain store
    __shared__ float wsum[4][NCLS];
    const int wave = tid >> 6;
    if ((tid & 63) == 0) {
#pragma unroll
        for (int k = 0; k < NCLS; ++k) wsum[wave][k] = cls[k];
    }
    __syncthreads();
    if (tid < NCLS) {
        const float scale = 1.0f / (float)Cd;   // channel mean
        float s = (wsum[0][tid] + wsum[1][tid]) + (wsum[2][tid] + wsum[3][tid]);
        // slot layout: [(b*NCCHUNK + z)*4 + x] * PSTRIDE + k
        const size_t slot = ((size_t)b * NCCHUNK + blockIdx.z) * 4 + blockIdx.x;
        psum[slot * PSTRIDE + tid] = s * scale;
    }

    // counts: z==0 blocks cover each (batch, hw-quarter) exactly once
    if (blockIdx.z == 0) {
        float cnt[NCLS] = {0, 0, 0, 0, 0};
        int mm[4] = {m.x, m.y, m.z, m.w};
#pragma unroll
        for (int e = 0; e < 4; ++e) {
#pragma unroll
            for (int k = 0; k < NCLS; ++k)
                cnt[k] += (mm[e] == k) ? 1.0f : 0.0f;
        }
#pragma unroll
        for (int k = 0; k < NCLS; ++k) {
#pragma unroll
            for (int off = 32; off > 0; off >>= 1)
                cnt[k] += __shfl_down(cnt[k], off, 64);
        }
        __shared__ float wcnt[4][NCLS];
        if ((tid & 63) == 0) {
#pragma unroll
            for (int k = 0; k < NCLS; ++k) wcnt[wave][k] = cnt[k];
        }
        __syncthreads();
        if (tid < NCLS) {
            float c = (wcnt[0][tid] + wcnt[1][tid]) + (wcnt[2][tid] + wcnt[3][tid]);
            pcnt[((size_t)b * 4 + blockIdx.x) * PSTRIDE + tid] = c;
        }
    }
}

// Kernel 2: pre-reduce 128 partials per segment, then 80 segments -> scalar.
__global__ __launch_bounds__(128) void finalize_kernel(
    const float* __restrict__ psum, const float* __restrict__ pcnt,
    float* __restrict__ out)
{
    __shared__ float sMax[128];
    __shared__ float sSum[128];
    const int t = threadIdx.x;

    float s = 0.0f, cnt = 0.0f;
    if (t < Bd * NCLS) {
        const int b = t / NCLS, k = t % NCLS;
        const float* p = psum + (size_t)b * NCCHUNK * 4 * PSTRIDE + k;
#pragma unroll 8
        for (int j = 0; j < NCCHUNK * 4; ++j) s += p[(size_t)j * PSTRIDE];
        const float* q = pcnt + (size_t)b * 4 * PSTRIDE + k;
        cnt = (q[0] + q[PSTRIDE]) + (q[2 * PSTRIDE] + q[3 * PSTRIDE]);
    }
    const float avg = s / fmaxf(cnt, 1.0f);   // empty segments -> 0 (contribute nothing)

    sMax[t] = avg;
    __syncthreads();
#pragma unroll
    for (int off = 64; off > 0; off >>= 1) {
        if (t < off) sMax[t] = fmaxf(sMax[t], sMax[t + off]);
        __syncthreads();
    }
    const float wmax = sMax[0];

    float w = (wmax > 0.0f) ? (avg / (wmax + EPS2)) : (avg + EPS2);
    w = fminf(fmaxf(w, 0.0f), 1.0f);

    sSum[t] = s * (w * BETA + 1.0f);
    __syncthreads();
#pragma unroll
    for (int off = 64; off > 0; off >>= 1) {
        if (t < off) sSum[t] += sSum[t + off];
        __syncthreads();
    }
    if (t == 0) out[0] = sSum[0] / (float)(Bd * HWd);
}

extern "C" void kernel_launch(void* const* d_in, const int* in_sizes, int n_in,
                              void* d_out, int out_size, void* d_ws, size_t ws_size,
                              hipStream_t stream) {
    const float* rec  = (const float*)d_in[0];
    const float* aln  = (const float*)d_in[1];
    const int*   mask = (const int*)d_in[2];
    float* out = (float*)d_out;

    // ws layout: [2048 * 8] sum partials (64KB) | [64 * 8] count partials (2KB)
    float* psum = (float*)d_ws;
    float* pcnt = psum + (size_t)2048 * PSTRIDE;
    // no memset needed: every slot is unconditionally overwritten each launch

    dim3 grid(HWd / PIX_PER_BLOCK, Bd, NCCHUNK);   // (4, 16, 32) = 2048 blocks
    seg_partial_kernel<<<grid, 256, 0, stream>>>(rec, aln, mask, psum, pcnt);
    finalize_kernel<<<1, 128, 0, stream>>>(psum, pcnt, out);
}